// Round 6
// baseline (240.606 us; speedup 1.0000x reference)
//
#include <hip/hip_runtime.h>
#include <hip/hip_bf16.h>

#define N_NODES 50000
#define N_EDGES 400000   // divisible by 32
#define D 16
#define HID 64

#define SCAN_B 256
#define SCAN_G ((N_NODES + SCAN_B - 1) / SCAN_B)   // 196
#define EPB 32                                     // edges per block-iteration

typedef __attribute__((ext_vector_type(8))) short bf16x8;
typedef __attribute__((ext_vector_type(4))) float f32x4;
typedef unsigned short ushort_t;

// ---------------- int-indexed workspace layout (CSR/MFMA path) ----------------
#define CNT4_OFF  0                       // [4][N] replicated counts
#define DEG_OFF   (4 * N_NODES)           // [N] total degree
#define OFF_OFF   (5 * N_NODES)           // [N+1] CSR offsets
#define CUR_OFF   (6 * N_NODES + 1)       // [N] claim cursors
#define BS_OFF    (7 * N_NODES + 1)       // [SCAN_G] block sums
#define FLAGS_I   (BS_OFF + SCAN_G)       // [2] dtype flags
#define MSG_OFF_I (((FLAGS_I + 2) + 3) & ~3)  // [2E*16] float msgs, 16B-aligned
#define CSR_NEEDED_BYTES ((size_t)(MSG_OFF_I + 2 * N_EDGES * D) * 4 + 64)

// ---------------- fallback (atomic) layout ----------------
#define FB_NDEG   (N_NODES)
#define FB_NACC   (N_NODES * D)
#define FB_FLAGS  (FB_NDEG + FB_NACC)

// ---------------------------------------------------------------------------
// dtype helpers
// ---------------------------------------------------------------------------
__device__ __forceinline__ float bf_bits(ushort_t us) {
    return __uint_as_float(((unsigned)us) << 16);
}
__device__ __forceinline__ ushort_t f2bf(float v) {   // round-to-nearest-even
    unsigned u = __float_as_uint(v);
    unsigned r = (u + 0x7fffu + ((u >> 16) & 1u)) >> 16;
    return (ushort_t)r;
}
__device__ __forceinline__ float ld_f(const void* p, int idx, int f32) {
    return f32 ? ((const float*)p)[idx]
               : bf_bits(((const ushort_t*)p)[idx]);
}
__device__ __forceinline__ ushort_t ld_bf_bits(const void* p, int idx, int f32) {
    return f32 ? f2bf(((const float*)p)[idx]) : ((const ushort_t*)p)[idx];
}

__device__ __forceinline__ void load16(const void* __restrict__ p, long long base,
                                       int f32, float* o) {
    if (f32) {
        const float4* q = (const float4*)((const float*)p + base);
        float4 a = q[0], b = q[1], c = q[2], d = q[3];
        o[0]=a.x; o[1]=a.y; o[2]=a.z; o[3]=a.w;
        o[4]=b.x; o[5]=b.y; o[6]=b.z; o[7]=b.w;
        o[8]=c.x; o[9]=c.y; o[10]=c.z; o[11]=c.w;
        o[12]=d.x; o[13]=d.y; o[14]=d.z; o[15]=d.w;
    } else {
        const uint4* q = (const uint4*)((const ushort_t*)p + base);
        uint4 a = q[0], b = q[1];
        unsigned u[8] = {a.x, a.y, a.z, a.w, b.x, b.y, b.z, b.w};
#pragma unroll
        for (int k = 0; k < 8; k++) {
            o[2 * k]     = __uint_as_float(u[k] << 16);
            o[2 * k + 1] = __uint_as_float(u[k] & 0xffff0000u);
        }
    }
}

// load one node-row (16 values) as 2 uint4 of packed bf16 bits
__device__ __forceinline__ void load_row_bf16(const void* __restrict__ x, long long node,
                                              int f32, uint4& a, uint4& b) {
    if (!f32) {
        const uint4* p = (const uint4*)((const ushort_t*)x + node * D);
        a = p[0]; b = p[1];
    } else {
        union { ushort_t u[16]; uint4 q[2]; } t;
#pragma unroll
        for (int k = 0; k < 16; k++) t.u[k] = f2bf(((const float*)x)[node * D + k]);
        a = t.q[0]; b = t.q[1];
    }
}

__device__ __forceinline__ void load_edge(const void* __restrict__ ei, int e, int is64,
                                          int& s, int& d) {
    if (is64) {
        const long long* p = (const long long*)ei;
        s = (int)p[e];
        d = (int)p[N_EDGES + e];
    } else {
        const int* p = (const int*)ei;
        s = p[e];
        d = p[N_EDGES + e];
    }
}

__device__ __forceinline__ void detect_flags(const void* x, const void* ei, int* flags) {
    const ushort_t* h = (const ushort_t*)x;
    int f32 = 0;
    for (int k = 0; k < 256; k++) {
        float v = bf_bits(h[k]);
        if (!(v == v) || fabsf(v) > 1.0e6f) { f32 = 1; break; }
    }
    const long long* p = (const long long*)ei;
    int i64 = 1;
    for (int k = 0; k < 16; k++) {
        long long v = p[k];
        if (v < 0 || v >= N_NODES) { i64 = 0; break; }
    }
    flags[0] = f32;
    flags[1] = i64;
}

__device__ __forceinline__ float red16(float v) {   // sum over 16-lane group
    v += __shfl_xor(v, 1);
    v += __shfl_xor(v, 2);
    v += __shfl_xor(v, 4);
    v += __shfl_xor(v, 8);
    return v;
}

// ===========================================================================
// CSR/MFMA path kernels
// ===========================================================================
__global__ void csr_init_kernel(int* __restrict__ wsI,
                                const void* __restrict__ x,
                                const void* __restrict__ ei) {
    int i = blockIdx.x * blockDim.x + threadIdx.x;
    if (i < 4 * N_NODES) wsI[CNT4_OFF + i] = 0;
    if (blockIdx.x == 0 && threadIdx.x == 0)
        detect_flags(x, ei, wsI + FLAGS_I);
}

__global__ void csr_count_kernel(const void* __restrict__ ei, int* __restrict__ wsI) {
    int i64 = wsI[FLAGS_I + 1];
    int e = blockIdx.x * blockDim.x + threadIdx.x;
    if (e >= N_EDGES) return;
    int s, d;
    load_edge(ei, e, i64, s, d);
    int r = (e & 3) * N_NODES;
    atomicAdd(&wsI[CNT4_OFF + r + s], 1);
    atomicAdd(&wsI[CNT4_OFF + r + d], 1);
}

// scan1: fold replicas -> DEG, per-block sums -> BS
__global__ __launch_bounds__(SCAN_B) void csr_scan1_kernel(int* __restrict__ wsI) {
    __shared__ int sm[SCAN_B];
    int t = threadIdx.x;
    int g = blockIdx.x * SCAN_B + t;
    int c = 0;
    if (g < N_NODES) {
        c = wsI[CNT4_OFF + g] + wsI[CNT4_OFF + N_NODES + g]
          + wsI[CNT4_OFF + 2 * N_NODES + g] + wsI[CNT4_OFF + 3 * N_NODES + g];
        wsI[DEG_OFF + g] = c;
    }
    sm[t] = c;
    __syncthreads();
    for (int st = SCAN_B / 2; st > 0; st >>= 1) {
        if (t < st) sm[t] += sm[t + st];
        __syncthreads();
    }
    if (t == 0) wsI[BS_OFF + blockIdx.x] = sm[0];
}

// scan3 (merged scan2): every block scans BS locally, then its own chunk.
__global__ __launch_bounds__(SCAN_B) void csr_scan3_kernel(int* __restrict__ wsI) {
    __shared__ int sB[SCAN_B];
    __shared__ int sm[SCAN_B];
    int t = threadIdx.x;
    int bsv = (t < SCAN_G) ? wsI[BS_OFF + t] : 0;
    sB[t] = bsv;
    __syncthreads();
    for (int st = 1; st < SCAN_B; st <<= 1) {
        int u = (t >= st) ? sB[t - st] : 0;
        __syncthreads();
        sB[t] += u;
        __syncthreads();
    }
    int blockBase = sB[blockIdx.x] - wsI[BS_OFF + blockIdx.x];   // exclusive prefix

    int g = blockIdx.x * SCAN_B + t;
    int c = (g < N_NODES) ? wsI[DEG_OFF + g] : 0;
    sm[t] = c;
    __syncthreads();
    for (int st = 1; st < SCAN_B; st <<= 1) {
        int u = (t >= st) ? sm[t - st] : 0;
        __syncthreads();
        sm[t] += u;
        __syncthreads();
    }
    int excl = sm[t] - c + blockBase;
    if (g < N_NODES) {
        wsI[OFF_OFF + g] = excl;
        wsI[CUR_OFF + g] = excl;
        if (g == N_NODES - 1) wsI[OFF_OFF + N_NODES] = excl + c;
    }
}

// ---------------------------------------------------------------------------
// MFMA edge kernel. Block = 256 threads = 4 waves; 32 edges per iteration.
// A-rows (64 x 32 bf16): row 2i=[xs|xd], row 2i+1=[xd|xs].
// Wave w computes M-tile rows 16w..16w+15 (edges 8w..8w+7 block-local).
// Verified gfx950 layouts: A/B frag [m|n=lane&15][k=(lane>>4)*8+j],
// C/D: col=lane&15, row=(lane>>4)*4+reg.
// ---------------------------------------------------------------------------
#define SA_STRIDE 40   // shorts per A-row (80B, 16B-aligned)
#define SH_STRIDE 80   // shorts per h-row (160B, 16B-aligned)

__global__ __launch_bounds__(256) void csr_edge_mfma_kernel(
    const void* __restrict__ x,
    const void* __restrict__ ei,
    const void* __restrict__ W1,   // [64][32] row-major
    const void* __restrict__ b1,   // [64]
    const void* __restrict__ W2,   // [16][64] row-major
    const void* __restrict__ b2,   // [16]
    int* __restrict__ wsI)
{
    __shared__ __align__(16) short sA[64 * SA_STRIDE];
    __shared__ __align__(16) short sH[4][16 * SH_STRIDE];
    __shared__ int   sSlot[64];
    __shared__ float sCoef[32];

    const int f32 = wsI[FLAGS_I];
    const int i64 = wsI[FLAGS_I + 1];
    float* msg = (float*)(wsI + MSG_OFF_I);

    const int tid = threadIdx.x;
    const int w  = tid >> 6;        // wave 0..3
    const int lm = tid & 63;        // lane
    const int m  = lm & 15;
    const int q  = lm >> 4;

    // ---- weight fragments in registers (wave-uniform data, per-lane slices) ----
    bf16x8 b1f[4];                  // B1[k][n] = W1[n][k]; n = 16*nt + m, k = 8q+j
#pragma unroll
    for (int nt = 0; nt < 4; nt++)
#pragma unroll
        for (int j = 0; j < 8; j++)
            b1f[nt][j] = (short)ld_bf_bits(W1, (16 * nt + m) * 32 + 8 * q + j, f32);
    bf16x8 b2f[2];                  // B2[k][n] = W2[n][k]; n = m, k = 32*kt + 8q+j
#pragma unroll
    for (int kt = 0; kt < 2; kt++)
#pragma unroll
        for (int j = 0; j < 8; j++)
            b2f[kt][j] = (short)ld_bf_bits(W2, m * 64 + 32 * kt + 8 * q + j, f32);
    float bias1v[4];
#pragma unroll
    for (int nt = 0; nt < 4; nt++) bias1v[nt] = ld_f(b1, 16 * nt + m, f32);
    const float bias2v = ld_f(b2, m, f32);

    for (long long base = (long long)blockIdx.x * EPB; base < N_EDGES;
         base += (long long)gridDim.x * EPB) {
        __syncthreads();   // previous iteration fully consumed sA/sSlot/sCoef

        // ---------------- staging: 8 role-threads per edge ----------------
        {
            int i = tid >> 3;        // edge 0..31 (block-local)
            int r = tid & 7;
            int e = (int)base + i;
            if (r < 4) {
                int s, d;
                load_edge(ei, e, i64, s, d);
                if (r == 0) {        // xs -> row 2i[0:16], row 2i+1[16:32]
                    uint4 a, b;
                    load_row_bf16(x, s, f32, a, b);
                    *(uint4*)&sA[(2 * i) * SA_STRIDE]          = a;
                    *(uint4*)&sA[(2 * i) * SA_STRIDE + 8]      = b;
                    *(uint4*)&sA[(2 * i + 1) * SA_STRIDE + 16] = a;
                    *(uint4*)&sA[(2 * i + 1) * SA_STRIDE + 24] = b;
                } else if (r == 1) { // xd -> row 2i[16:32], row 2i+1[0:16]
                    uint4 a, b;
                    load_row_bf16(x, d, f32, a, b);
                    *(uint4*)&sA[(2 * i) * SA_STRIDE + 16]     = a;
                    *(uint4*)&sA[(2 * i) * SA_STRIDE + 24]     = b;
                    *(uint4*)&sA[(2 * i + 1) * SA_STRIDE]      = a;
                    *(uint4*)&sA[(2 * i + 1) * SA_STRIDE + 8]  = b;
                } else if (r == 2) { // claim s-slot + coef
                    sSlot[2 * i] = atomicAdd(&wsI[CUR_OFF + s], 1);
                    float degs = (float)wsI[DEG_OFF + s];
                    float degd = (float)wsI[DEG_OFF + d];
                    sCoef[i] = (1.0f / sqrtf(fmaxf(degs, 1e-5f)))
                             * (1.0f / sqrtf(fmaxf(degd, 1e-5f)));
                } else {             // r == 3: claim d-slot
                    sSlot[2 * i + 1] = atomicAdd(&wsI[CUR_OFF + d], 1);
                }
            }
        }
        __syncthreads();

        // ---------------- layer 1: 4 MFMAs ----------------
        bf16x8 a1 = *(const bf16x8*)&sA[(16 * w + m) * SA_STRIDE + q * 8];
        f32x4 z4 = {0.0f, 0.0f, 0.0f, 0.0f};
        f32x4 hacc[4];
#pragma unroll
        for (int nt = 0; nt < 4; nt++)
            hacc[nt] = __builtin_amdgcn_mfma_f32_16x16x32_bf16(a1, b1f[nt], z4, 0, 0, 0);

        // bias + relu + bf16, transpose via per-wave LDS
#pragma unroll
        for (int nt = 0; nt < 4; nt++)
#pragma unroll
            for (int r = 0; r < 4; r++) {
                float hv = fmaxf(hacc[nt][r] + bias1v[nt], 0.0f);
                sH[w][(4 * q + r) * SH_STRIDE + 16 * nt + m] = (short)f2bf(hv);
            }
        __syncthreads();   // uniform across block; makes sH visible wave-locally too

        // ---------------- layer 2: 2 MFMAs ----------------
        bf16x8 a20 = *(const bf16x8*)&sH[w][m * SH_STRIDE + q * 8];
        bf16x8 a21 = *(const bf16x8*)&sH[w][m * SH_STRIDE + 32 + q * 8];
        f32x4 vacc = __builtin_amdgcn_mfma_f32_16x16x32_bf16(a20, b2f[0], z4, 0, 0, 0);
        vacc = __builtin_amdgcn_mfma_f32_16x16x32_bf16(a21, b2f[1], vacc, 0, 0, 0);

        // ---------------- epilogue: normalize, Householder, store ----------------
        // lane holds v[row=4q+r][dim=m]; rows 4q..4q+3 = edges (8w+2q) s,d and (8w+2q+1) s,d
        float vn[4];
#pragma unroll
        for (int r = 0; r < 4; r++) {
            float v = vacc[r] + bias2v;
            float nsq = red16(v * v);
            vn[r] = v * (1.0f / fmaxf(sqrtf(nsq), 1e-12f));
        }
        int rowA = 16 * w + 4 * q;
        float xsA = bf_bits((ushort_t)sA[rowA * SA_STRIDE + m]);
        float xdA = bf_bits((ushort_t)sA[rowA * SA_STRIDE + 16 + m]);
        float xsB = bf_bits((ushort_t)sA[(rowA + 2) * SA_STRIDE + m]);
        float xdB = bf_bits((ushort_t)sA[(rowA + 2) * SA_STRIDE + 16 + m]);
        int iA = 8 * w + 2 * q;
        float cA = sCoef[iA], cB = sCoef[iA + 1];

        // edge A: vs=vn[0], vd=vn[1]
        {
            float d1 = red16(vn[1] * xdA);
            float t  = fmaf(-2.0f * d1, vn[1], xdA);
            float d2 = red16(vn[0] * t);
            float ms = cA * fmaf(-2.0f * d2, vn[0], t);
            float d3 = red16(vn[0] * xsA);
            float u  = fmaf(-2.0f * d3, vn[0], xsA);
            float d4 = red16(vn[1] * u);
            float md = cA * fmaf(-2.0f * d4, vn[1], u);
            msg[(long long)sSlot[2 * iA] * D + m]     = ms;
            msg[(long long)sSlot[2 * iA + 1] * D + m] = md;
        }
        // edge B: vs=vn[2], vd=vn[3]
        {
            float d1 = red16(vn[3] * xdB);
            float t  = fmaf(-2.0f * d1, vn[3], xdB);
            float d2 = red16(vn[2] * t);
            float ms = cB * fmaf(-2.0f * d2, vn[2], t);
            float d3 = red16(vn[2] * xsB);
            float u  = fmaf(-2.0f * d3, vn[2], xsB);
            float d4 = red16(vn[3] * u);
            float md = cB * fmaf(-2.0f * d4, vn[3], u);
            msg[(long long)sSlot[2 * iA + 2] * D + m] = ms;
            msg[(long long)sSlot[2 * iA + 3] * D + m] = md;
        }
    }
}

// 16 lanes per node; lane i sums dim i over the node's contiguous msg range.
__global__ __launch_bounds__(256) void csr_gather_kernel(
    const void* __restrict__ x,
    const int* __restrict__ wsI,
    void* __restrict__ out)
{
    int f32 = wsI[FLAGS_I];
    int n = blockIdx.x * 16 + (threadIdx.x >> 4);
    int i = threadIdx.x & 15;
    if (n >= N_NODES) return;

    const int* off = wsI + OFF_OFF;
    const float* msg = (const float*)(wsI + MSG_OFF_I);

    int beg = off[n], end = off[n + 1];
    float a = 0.0f;
    for (int it = beg; it < end; it++)
        a += msg[(long long)it * D + i];
    float v = ld_f(x, n * D + i, f32) + a;
    v = fmaxf(v, 0.0f);
    if (f32) ((float*)out)[n * D + i] = v;
    else     ((__hip_bfloat16*)out)[n * D + i] = __float2bfloat16(v);
}

// ===========================================================================
// Fallback path (R3 structure, known-good): float atomics into acc
// ===========================================================================
__device__ __forceinline__ void edge_math(
    const float* __restrict__ sW1, const float* __restrict__ sW2t,
    const float* __restrict__ sb1, const float* __restrict__ sb2,
    const float* xs, const float* xd, float coef,
    float* ms, float* md)
{
    float vs[D], vd[D];
#pragma unroll
    for (int i = 0; i < D; i++) { vs[i] = sb2[i]; vd[i] = sb2[i]; }
#pragma unroll 4
    for (int j = 0; j < HID; j++) {
        float hs = sb1[j], hd = sb1[j];
        const float* w = &sW1[j * 2 * D];
#pragma unroll
        for (int k = 0; k < D; k++) {
            float w0 = w[k], w1 = w[D + k];
            hs = fmaf(w0, xs[k], hs);
            hs = fmaf(w1, xd[k], hs);
            hd = fmaf(w0, xd[k], hd);
            hd = fmaf(w1, xs[k], hd);
        }
        hs = fmaxf(hs, 0.0f);
        hd = fmaxf(hd, 0.0f);
        const float* w2 = &sW2t[j * D];
#pragma unroll
        for (int i = 0; i < D; i++) {
            vs[i] = fmaf(w2[i], hs, vs[i]);
            vd[i] = fmaf(w2[i], hd, vd[i]);
        }
    }
    float ns = 0.0f, nd = 0.0f;
#pragma unroll
    for (int i = 0; i < D; i++) { ns = fmaf(vs[i], vs[i], ns); nd = fmaf(vd[i], vd[i], nd); }
    float is_ = 1.0f / fmaxf(sqrtf(ns), 1e-12f);
    float id_ = 1.0f / fmaxf(sqrtf(nd), 1e-12f);
#pragma unroll
    for (int i = 0; i < D; i++) { vs[i] *= is_; vd[i] *= id_; }
    float dot1 = 0.0f;
#pragma unroll
    for (int i = 0; i < D; i++) dot1 = fmaf(vd[i], xd[i], dot1);
#pragma unroll
    for (int i = 0; i < D; i++) ms[i] = fmaf(-2.0f * dot1, vd[i], xd[i]);
    float dot2 = 0.0f;
#pragma unroll
    for (int i = 0; i < D; i++) dot2 = fmaf(vs[i], ms[i], dot2);
#pragma unroll
    for (int i = 0; i < D; i++) ms[i] = coef * fmaf(-2.0f * dot2, vs[i], ms[i]);
    float dot3 = 0.0f;
#pragma unroll
    for (int i = 0; i < D; i++) dot3 = fmaf(vs[i], xs[i], dot3);
#pragma unroll
    for (int i = 0; i < D; i++) md[i] = fmaf(-2.0f * dot3, vs[i], xs[i]);
    float dot4 = 0.0f;
#pragma unroll
    for (int i = 0; i < D; i++) dot4 = fmaf(vd[i], md[i], dot4);
#pragma unroll
    for (int i = 0; i < D; i++) md[i] = coef * fmaf(-2.0f * dot4, vd[i], md[i]);
}

__device__ __forceinline__ void stage_weights(
    const void* W1, const void* b1, const void* W2, const void* b2, int f32,
    float* sW1, float* sW2t, float* sb1, float* sb2)
{
    int t = threadIdx.x;
    for (int idx = t; idx < HID * 2 * D; idx += blockDim.x)
        sW1[idx] = ld_f(W1, idx, f32);
    for (int idx = t; idx < HID * D; idx += blockDim.x) {
        int j = idx / D, i = idx % D;
        sW2t[idx] = ld_f(W2, i * HID + j, f32);
    }
    if (t < HID) sb1[t] = ld_f(b1, t, f32);
    if (t < D)  sb2[t] = ld_f(b2, t, f32);
}

__global__ void fb_init_kernel(float* __restrict__ ws,
                               const void* __restrict__ x,
                               const void* __restrict__ ei) {
    int i = blockIdx.x * blockDim.x + threadIdx.x;
    if (i < FB_FLAGS) ws[i] = 0.0f;
    if (blockIdx.x == 0 && threadIdx.x == 0)
        detect_flags(x, ei, (int*)(ws + FB_FLAGS));
}

__global__ void fb_deg_kernel(const void* __restrict__ ei, float* __restrict__ ws) {
    int i64 = ((const int*)(ws + FB_FLAGS))[1];
    int e = blockIdx.x * blockDim.x + threadIdx.x;
    if (e >= N_EDGES) return;
    int s, d;
    load_edge(ei, e, i64, s, d);
    atomicAdd(&ws[s], 1.0f);
    atomicAdd(&ws[d], 1.0f);
}

__global__ __launch_bounds__(256) void fb_edge_kernel(
    const void* __restrict__ x, const void* __restrict__ ei,
    const void* __restrict__ W1, const void* __restrict__ b1,
    const void* __restrict__ W2, const void* __restrict__ b2,
    float* __restrict__ ws)
{
    __shared__ __align__(16) float sW1[HID * 2 * D];
    __shared__ __align__(16) float sW2t[HID * D];
    __shared__ float sb1[HID];
    __shared__ float sb2[D];
    const int* flags = (const int*)(ws + FB_FLAGS);
    int f32 = flags[0], i64 = flags[1];
    stage_weights(W1, b1, W2, b2, f32, sW1, sW2t, sb1, sb2);
    __syncthreads();
    int e = blockIdx.x * blockDim.x + threadIdx.x;
    if (e >= N_EDGES) return;
    int s, d;
    load_edge(ei, e, i64, s, d);
    float xs[D], xd[D];
    load16(x, (long long)s * D, f32, xs);
    load16(x, (long long)d * D, f32, xd);
    float coef = (1.0f / sqrtf(fmaxf(ws[s], 1e-5f))) * (1.0f / sqrtf(fmaxf(ws[d], 1e-5f)));
    float ms[D], md[D];
    edge_math(sW1, sW2t, sb1, sb2, xs, xd, coef, ms, md);
    float* acc = ws + FB_NDEG;
#pragma unroll
    for (int i = 0; i < D; i++) atomicAdd(&acc[(long long)s * D + i], ms[i]);
#pragma unroll
    for (int i = 0; i < D; i++) atomicAdd(&acc[(long long)d * D + i], md[i]);
}

__global__ void fb_finalize_kernel(const void* __restrict__ x,
                                   const float* __restrict__ ws,
                                   void* __restrict__ out)
{
    int f32 = ((const int*)(ws + FB_FLAGS))[0];
    const float* acc = ws + FB_NDEG;
    int i = blockIdx.x * blockDim.x + threadIdx.x;
    if (i >= FB_NACC) return;
    float v = ld_f(x, i, f32) + acc[i];
    v = fmaxf(v, 0.0f);
    if (f32) ((float*)out)[i] = v;
    else     ((__hip_bfloat16*)out)[i] = __float2bfloat16(v);
}

// ===========================================================================
extern "C" void kernel_launch(void* const* d_in, const int* in_sizes, int n_in,
                              void* d_out, int out_size, void* d_ws, size_t ws_size,
                              hipStream_t stream)
{
    const void* x  = d_in[0];
    const void* ei = d_in[1];
    const void* W1 = d_in[2];
    const void* b1 = d_in[3];
    const void* W2 = d_in[4];
    const void* b2 = d_in[5];

    int blk = 256;
    if (ws_size >= CSR_NEEDED_BYTES) {
        int* wsI = (int*)d_ws;
        csr_init_kernel<<<(4 * N_NODES + blk - 1) / blk, blk, 0, stream>>>(wsI, x, ei);
        csr_count_kernel<<<(N_EDGES + blk - 1) / blk, blk, 0, stream>>>(ei, wsI);
        csr_scan1_kernel<<<SCAN_G, SCAN_B, 0, stream>>>(wsI);
        csr_scan3_kernel<<<SCAN_G, SCAN_B, 0, stream>>>(wsI);
        csr_edge_mfma_kernel<<<2048, blk, 0, stream>>>(x, ei, W1, b1, W2, b2, wsI);
        csr_gather_kernel<<<(N_NODES + 15) / 16, blk, 0, stream>>>(x, wsI, d_out);
    } else {
        float* ws = (float*)d_ws;
        fb_init_kernel<<<(FB_FLAGS + blk - 1) / blk, blk, 0, stream>>>(ws, x, ei);
        fb_deg_kernel<<<(N_EDGES + blk - 1) / blk, blk, 0, stream>>>(ei, ws);
        fb_edge_kernel<<<(N_EDGES + blk - 1) / blk, blk, 0, stream>>>(x, ei, W1, b1, W2, b2, ws);
        fb_finalize_kernel<<<(FB_NACC + blk - 1) / blk, blk, 0, stream>>>(x, ws, d_out);
    }
}

// Round 7
// 201.351 us; speedup vs baseline: 1.1950x; 1.1950x over previous
//
#include <hip/hip_runtime.h>
#include <hip/hip_bf16.h>

#define N_NODES 50000
#define N_EDGES 400000
#define D 16
#define HID 64

#define SCAN_B 256
#define SCAN_G ((N_NODES + SCAN_B - 1) / SCAN_B)   // 196

typedef unsigned short ushort_t;

// ---------------- int-indexed workspace layout (CSR path) ----------------
#define CNT4_OFF  0                       // [4][N] replicated counts
#define DEG_OFF   (4 * N_NODES)           // [N] total degree
#define OFF_OFF   (5 * N_NODES)           // [N+1] CSR offsets
#define CUR_OFF   (6 * N_NODES + 1)       // [N] claim cursors
#define BS_OFF    (7 * N_NODES + 1)       // [SCAN_G] block sums
#define FLAGS_I   (BS_OFF + SCAN_G)       // [2] dtype flags
#define MSG_OFF_I (((FLAGS_I + 2) + 3) & ~3)  // [2E*16] float msgs, 16B-aligned
#define CSR_NEEDED_BYTES ((size_t)(MSG_OFF_I + 2 * N_EDGES * D) * 4 + 64)

// ---------------- fallback (atomic) layout ----------------
#define FB_NDEG   (N_NODES)
#define FB_NACC   (N_NODES * D)
#define FB_FLAGS  (FB_NDEG + FB_NACC)

// ---------------------------------------------------------------------------
// dtype helpers
// ---------------------------------------------------------------------------
__device__ __forceinline__ float bf_bits(ushort_t us) {
    return __uint_as_float(((unsigned)us) << 16);
}
__device__ __forceinline__ ushort_t f2bf(float v) {   // round-to-nearest-even
    unsigned u = __float_as_uint(v);
    unsigned r = (u + 0x7fffu + ((u >> 16) & 1u)) >> 16;
    return (ushort_t)r;
}
__device__ __forceinline__ float ld_f(const void* p, int idx, int f32) {
    return f32 ? ((const float*)p)[idx]
               : bf_bits(((const ushort_t*)p)[idx]);
}

__device__ __forceinline__ void load16(const void* __restrict__ p, long long base,
                                       int f32, float* o) {
    if (f32) {
        const float4* q = (const float4*)((const float*)p + base);
        float4 a = q[0], b = q[1], c = q[2], d = q[3];
        o[0]=a.x; o[1]=a.y; o[2]=a.z; o[3]=a.w;
        o[4]=b.x; o[5]=b.y; o[6]=b.z; o[7]=b.w;
        o[8]=c.x; o[9]=c.y; o[10]=c.z; o[11]=c.w;
        o[12]=d.x; o[13]=d.y; o[14]=d.z; o[15]=d.w;
    } else {
        const uint4* q = (const uint4*)((const ushort_t*)p + base);
        uint4 a = q[0], b = q[1];
        unsigned u[8] = {a.x, a.y, a.z, a.w, b.x, b.y, b.z, b.w};
#pragma unroll
        for (int k = 0; k < 8; k++) {
            o[2 * k]     = __uint_as_float(u[k] << 16);
            o[2 * k + 1] = __uint_as_float(u[k] & 0xffff0000u);
        }
    }
}

__device__ __forceinline__ void load_edge(const void* __restrict__ ei, int e, int is64,
                                          int& s, int& d) {
    if (is64) {
        const long long* p = (const long long*)ei;
        s = (int)p[e];
        d = (int)p[N_EDGES + e];
    } else {
        const int* p = (const int*)ei;
        s = p[e];
        d = p[N_EDGES + e];
    }
}

__device__ __forceinline__ void detect_flags(const void* x, const void* ei, int* flags) {
    const ushort_t* h = (const ushort_t*)x;
    int f32 = 0;
    for (int k = 0; k < 256; k++) {
        float v = bf_bits(h[k]);
        if (!(v == v) || fabsf(v) > 1.0e6f) { f32 = 1; break; }
    }
    const long long* p = (const long long*)ei;
    int i64 = 1;
    for (int k = 0; k < 16; k++) {
        long long v = p[k];
        if (v < 0 || v >= N_NODES) { i64 = 0; break; }
    }
    flags[0] = f32;
    flags[1] = i64;
}

__device__ __forceinline__ void stage_weights(
    const void* W1, const void* b1, const void* W2, const void* b2, int f32,
    float* sW1, float* sW2t, float* sb1, float* sb2)
{
    int t = threadIdx.x;
    for (int idx = t; idx < HID * 2 * D; idx += blockDim.x)
        sW1[idx] = ld_f(W1, idx, f32);
    for (int idx = t; idx < HID * D; idx += blockDim.x) {
        int j = idx / D, i = idx % D;
        sW2t[idx] = ld_f(W2, i * HID + j, f32);
    }
    if (t < HID) sb1[t] = ld_f(b1, t, f32);
    if (t < D)  sb2[t] = ld_f(b2, t, f32);
}

// ---------------------------------------------------------------------------
// Per-edge math with vectorized (b128) LDS weight reads.
//   ms = coef*Hs(Hd(xd)), md = coef*Hd(Hs(xs))
// ---------------------------------------------------------------------------
__device__ __forceinline__ void edge_math_v4(
    const float* __restrict__ sW1, const float* __restrict__ sW2t,
    const float* __restrict__ sb1, const float* __restrict__ sb2,
    const float* xs, const float* xd, float coef,
    float* ms, float* md)
{
    float vs[D], vd[D];
#pragma unroll
    for (int i = 0; i < D; i++) { vs[i] = sb2[i]; vd[i] = sb2[i]; }

#pragma unroll 4
    for (int j = 0; j < HID; j++) {
        float hs = sb1[j], hd = sb1[j];
        const float4* w4 = (const float4*)&sW1[j * 2 * D];   // 8 vec4: [0:4)=xs-w, [4:8)=xd-w
#pragma unroll
        for (int t = 0; t < 4; t++) {
            float4 wv = w4[t];
            int k = 4 * t;
            hs = fmaf(wv.x, xs[k],     hs); hd = fmaf(wv.x, xd[k],     hd);
            hs = fmaf(wv.y, xs[k + 1], hs); hd = fmaf(wv.y, xd[k + 1], hd);
            hs = fmaf(wv.z, xs[k + 2], hs); hd = fmaf(wv.z, xd[k + 2], hd);
            hs = fmaf(wv.w, xs[k + 3], hs); hd = fmaf(wv.w, xd[k + 3], hd);
        }
#pragma unroll
        for (int t = 0; t < 4; t++) {
            float4 wv = w4[4 + t];
            int k = 4 * t;
            hs = fmaf(wv.x, xd[k],     hs); hd = fmaf(wv.x, xs[k],     hd);
            hs = fmaf(wv.y, xd[k + 1], hs); hd = fmaf(wv.y, xs[k + 1], hd);
            hs = fmaf(wv.z, xd[k + 2], hs); hd = fmaf(wv.z, xs[k + 2], hd);
            hs = fmaf(wv.w, xd[k + 3], hs); hd = fmaf(wv.w, xs[k + 3], hd);
        }
        hs = fmaxf(hs, 0.0f);
        hd = fmaxf(hd, 0.0f);
        const float4* w24 = (const float4*)&sW2t[j * D];     // 4 vec4
#pragma unroll
        for (int t = 0; t < 4; t++) {
            float4 u = w24[t];
            int i = 4 * t;
            vs[i]     = fmaf(u.x, hs, vs[i]);     vd[i]     = fmaf(u.x, hd, vd[i]);
            vs[i + 1] = fmaf(u.y, hs, vs[i + 1]); vd[i + 1] = fmaf(u.y, hd, vd[i + 1]);
            vs[i + 2] = fmaf(u.z, hs, vs[i + 2]); vd[i + 2] = fmaf(u.z, hd, vd[i + 2]);
            vs[i + 3] = fmaf(u.w, hs, vs[i + 3]); vd[i + 3] = fmaf(u.w, hd, vd[i + 3]);
        }
    }

    float ns = 0.0f, nd = 0.0f;
#pragma unroll
    for (int i = 0; i < D; i++) { ns = fmaf(vs[i], vs[i], ns); nd = fmaf(vd[i], vd[i], nd); }
    float is_ = 1.0f / fmaxf(sqrtf(ns), 1e-12f);
    float id_ = 1.0f / fmaxf(sqrtf(nd), 1e-12f);
#pragma unroll
    for (int i = 0; i < D; i++) { vs[i] *= is_; vd[i] *= id_; }

    float dot1 = 0.0f;
#pragma unroll
    for (int i = 0; i < D; i++) dot1 = fmaf(vd[i], xd[i], dot1);
#pragma unroll
    for (int i = 0; i < D; i++) ms[i] = fmaf(-2.0f * dot1, vd[i], xd[i]);
    float dot2 = 0.0f;
#pragma unroll
    for (int i = 0; i < D; i++) dot2 = fmaf(vs[i], ms[i], dot2);
#pragma unroll
    for (int i = 0; i < D; i++) ms[i] = coef * fmaf(-2.0f * dot2, vs[i], ms[i]);

    float dot3 = 0.0f;
#pragma unroll
    for (int i = 0; i < D; i++) dot3 = fmaf(vs[i], xs[i], dot3);
#pragma unroll
    for (int i = 0; i < D; i++) md[i] = fmaf(-2.0f * dot3, vs[i], xs[i]);
    float dot4 = 0.0f;
#pragma unroll
    for (int i = 0; i < D; i++) dot4 = fmaf(vd[i], md[i], dot4);
#pragma unroll
    for (int i = 0; i < D; i++) md[i] = coef * fmaf(-2.0f * dot4, vd[i], md[i]);
}

// ===========================================================================
// CSR path kernels
// ===========================================================================
__global__ void csr_init_kernel(int* __restrict__ wsI,
                                const void* __restrict__ x,
                                const void* __restrict__ ei) {
    int i = blockIdx.x * blockDim.x + threadIdx.x;
    if (i < 4 * N_NODES) wsI[CNT4_OFF + i] = 0;
    if (blockIdx.x == 0 && threadIdx.x == 0)
        detect_flags(x, ei, wsI + FLAGS_I);
}

__global__ void csr_count_kernel(const void* __restrict__ ei, int* __restrict__ wsI) {
    int i64 = wsI[FLAGS_I + 1];
    int e = blockIdx.x * blockDim.x + threadIdx.x;
    if (e >= N_EDGES) return;
    int s, d;
    load_edge(ei, e, i64, s, d);
    int r = (e & 3) * N_NODES;
    atomicAdd(&wsI[CNT4_OFF + r + s], 1);
    atomicAdd(&wsI[CNT4_OFF + r + d], 1);
}

// scan1: fold replicas -> DEG, per-block sums -> BS
__global__ __launch_bounds__(SCAN_B) void csr_scan1_kernel(int* __restrict__ wsI) {
    __shared__ int sm[SCAN_B];
    int t = threadIdx.x;
    int g = blockIdx.x * SCAN_B + t;
    int c = 0;
    if (g < N_NODES) {
        c = wsI[CNT4_OFF + g] + wsI[CNT4_OFF + N_NODES + g]
          + wsI[CNT4_OFF + 2 * N_NODES + g] + wsI[CNT4_OFF + 3 * N_NODES + g];
        wsI[DEG_OFF + g] = c;
    }
    sm[t] = c;
    __syncthreads();
    for (int st = SCAN_B / 2; st > 0; st >>= 1) {
        if (t < st) sm[t] += sm[t + st];
        __syncthreads();
    }
    if (t == 0) wsI[BS_OFF + blockIdx.x] = sm[0];
}

// scan3 (merged scan2): every block scans BS locally, then its own chunk.
__global__ __launch_bounds__(SCAN_B) void csr_scan3_kernel(int* __restrict__ wsI) {
    __shared__ int sB[SCAN_B];
    __shared__ int sm[SCAN_B];
    int t = threadIdx.x;
    int bsv = (t < SCAN_G) ? wsI[BS_OFF + t] : 0;
    sB[t] = bsv;
    __syncthreads();
    for (int st = 1; st < SCAN_B; st <<= 1) {
        int u = (t >= st) ? sB[t - st] : 0;
        __syncthreads();
        sB[t] += u;
        __syncthreads();
    }
    int blockBase = sB[blockIdx.x] - wsI[BS_OFF + blockIdx.x];   // exclusive prefix

    int g = blockIdx.x * SCAN_B + t;
    int c = (g < N_NODES) ? wsI[DEG_OFF + g] : 0;
    sm[t] = c;
    __syncthreads();
    for (int st = 1; st < SCAN_B; st <<= 1) {
        int u = (t >= st) ? sm[t - st] : 0;
        __syncthreads();
        sm[t] += u;
        __syncthreads();
    }
    int excl = sm[t] - c + blockBase;
    if (g < N_NODES) {
        wsI[OFF_OFF + g] = excl;
        wsI[CUR_OFF + g] = excl;
        if (g == N_NODES - 1) wsI[OFF_OFF + N_NODES] = excl + c;
    }
}

// Edge kernel: computes both messages, claims node-grouped slots directly.
__global__ __launch_bounds__(256) void csr_edge_kernel(
    const void* __restrict__ x,
    const void* __restrict__ ei,
    const void* __restrict__ W1,
    const void* __restrict__ b1,
    const void* __restrict__ W2,
    const void* __restrict__ b2,
    int* __restrict__ wsI)
{
    __shared__ __align__(16) float sW1[HID * 2 * D];
    __shared__ __align__(16) float sW2t[HID * D];
    __shared__ float sb1[HID];
    __shared__ float sb2[D];

    int f32 = wsI[FLAGS_I];
    int i64 = wsI[FLAGS_I + 1];
    stage_weights(W1, b1, W2, b2, f32, sW1, sW2t, sb1, sb2);
    __syncthreads();

    int e = blockIdx.x * blockDim.x + threadIdx.x;
    if (e >= N_EDGES) return;

    int s, d;
    load_edge(ei, e, i64, s, d);

    float xs[D], xd[D];
    load16(x, (long long)s * D, f32, xs);
    load16(x, (long long)d * D, f32, xd);

    float degs = (float)wsI[DEG_OFF + s];
    float degd = (float)wsI[DEG_OFF + d];
    float coef = (1.0f / sqrtf(fmaxf(degs, 1e-5f))) * (1.0f / sqrtf(fmaxf(degd, 1e-5f)));

    float ms[D], md[D];
    edge_math_v4(sW1, sW2t, sb1, sb2, xs, xd, coef, ms, md);

    float* msg = (float*)(wsI + MSG_OFF_I);
    int slot_s = atomicAdd(&wsI[CUR_OFF + s], 1);
    float4* m0 = (float4*)(msg + (long long)slot_s * D);
    m0[0] = make_float4(ms[0], ms[1], ms[2], ms[3]);
    m0[1] = make_float4(ms[4], ms[5], ms[6], ms[7]);
    m0[2] = make_float4(ms[8], ms[9], ms[10], ms[11]);
    m0[3] = make_float4(ms[12], ms[13], ms[14], ms[15]);
    int slot_d = atomicAdd(&wsI[CUR_OFF + d], 1);
    float4* m1 = (float4*)(msg + (long long)slot_d * D);
    m1[0] = make_float4(md[0], md[1], md[2], md[3]);
    m1[1] = make_float4(md[4], md[5], md[6], md[7]);
    m1[2] = make_float4(md[8], md[9], md[10], md[11]);
    m1[3] = make_float4(md[12], md[13], md[14], md[15]);
}

// Gather: 4 lanes per node, float4 per lane; unroll-2 accumulation.
__global__ __launch_bounds__(256) void csr_gather_kernel(
    const void* __restrict__ x,
    const int* __restrict__ wsI,
    void* __restrict__ out)
{
    int f32 = wsI[FLAGS_I];
    int n = blockIdx.x * 64 + (threadIdx.x >> 2);
    int c = threadIdx.x & 3;            // float4 chunk 0..3 (dims 4c..4c+3)
    if (n >= N_NODES) return;

    const int* off = wsI + OFF_OFF;
    const float4* msg4 = (const float4*)(wsI + MSG_OFF_I);

    int beg = off[n], end = off[n + 1];
    float4 a = make_float4(0.0f, 0.0f, 0.0f, 0.0f);
    int it = beg;
    for (; it + 2 <= end; it += 2) {
        float4 u = msg4[(long long)it * 4 + c];
        float4 v = msg4[(long long)(it + 1) * 4 + c];
        a.x += u.x + v.x; a.y += u.y + v.y; a.z += u.z + v.z; a.w += u.w + v.w;
    }
    if (it < end) {
        float4 u = msg4[(long long)it * 4 + c];
        a.x += u.x; a.y += u.y; a.z += u.z; a.w += u.w;
    }

    long long xb = (long long)n * D + 4 * c;
    float4 xv;
    if (f32) {
        xv = *(const float4*)((const float*)x + xb);
    } else {
        uint2 u = *(const uint2*)((const ushort_t*)x + xb);
        xv.x = __uint_as_float(u.x << 16);
        xv.y = __uint_as_float(u.x & 0xffff0000u);
        xv.z = __uint_as_float(u.y << 16);
        xv.w = __uint_as_float(u.y & 0xffff0000u);
    }
    float4 r;
    r.x = fmaxf(xv.x + a.x, 0.0f);
    r.y = fmaxf(xv.y + a.y, 0.0f);
    r.z = fmaxf(xv.z + a.z, 0.0f);
    r.w = fmaxf(xv.w + a.w, 0.0f);
    if (f32) {
        *(float4*)((float*)out + xb) = r;
    } else {
        uint2 o;
        o.x = (unsigned)f2bf(r.x) | ((unsigned)f2bf(r.y) << 16);
        o.y = (unsigned)f2bf(r.z) | ((unsigned)f2bf(r.w) << 16);
        *(uint2*)((ushort_t*)out + xb) = o;
    }
}

// ===========================================================================
// Fallback path (known-good): float atomics into acc
// ===========================================================================
__global__ void fb_init_kernel(float* __restrict__ ws,
                               const void* __restrict__ x,
                               const void* __restrict__ ei) {
    int i = blockIdx.x * blockDim.x + threadIdx.x;
    if (i < FB_FLAGS) ws[i] = 0.0f;
    if (blockIdx.x == 0 && threadIdx.x == 0)
        detect_flags(x, ei, (int*)(ws + FB_FLAGS));
}

__global__ void fb_deg_kernel(const void* __restrict__ ei, float* __restrict__ ws) {
    int i64 = ((const int*)(ws + FB_FLAGS))[1];
    int e = blockIdx.x * blockDim.x + threadIdx.x;
    if (e >= N_EDGES) return;
    int s, d;
    load_edge(ei, e, i64, s, d);
    atomicAdd(&ws[s], 1.0f);
    atomicAdd(&ws[d], 1.0f);
}

__global__ __launch_bounds__(256) void fb_edge_kernel(
    const void* __restrict__ x, const void* __restrict__ ei,
    const void* __restrict__ W1, const void* __restrict__ b1,
    const void* __restrict__ W2, const void* __restrict__ b2,
    float* __restrict__ ws)
{
    __shared__ __align__(16) float sW1[HID * 2 * D];
    __shared__ __align__(16) float sW2t[HID * D];
    __shared__ float sb1[HID];
    __shared__ float sb2[D];
    const int* flags = (const int*)(ws + FB_FLAGS);
    int f32 = flags[0], i64 = flags[1];
    stage_weights(W1, b1, W2, b2, f32, sW1, sW2t, sb1, sb2);
    __syncthreads();
    int e = blockIdx.x * blockDim.x + threadIdx.x;
    if (e >= N_EDGES) return;
    int s, d;
    load_edge(ei, e, i64, s, d);
    float xs[D], xd[D];
    load16(x, (long long)s * D, f32, xs);
    load16(x, (long long)d * D, f32, xd);
    float coef = (1.0f / sqrtf(fmaxf(ws[s], 1e-5f))) * (1.0f / sqrtf(fmaxf(ws[d], 1e-5f)));
    float ms[D], md[D];
    edge_math_v4(sW1, sW2t, sb1, sb2, xs, xd, coef, ms, md);
    float* acc = ws + FB_NDEG;
#pragma unroll
    for (int i = 0; i < D; i++) atomicAdd(&acc[(long long)s * D + i], ms[i]);
#pragma unroll
    for (int i = 0; i < D; i++) atomicAdd(&acc[(long long)d * D + i], md[i]);
}

__global__ void fb_finalize_kernel(const void* __restrict__ x,
                                   const float* __restrict__ ws,
                                   void* __restrict__ out)
{
    int f32 = ((const int*)(ws + FB_FLAGS))[0];
    const float* acc = ws + FB_NDEG;
    int i = blockIdx.x * blockDim.x + threadIdx.x;
    if (i >= FB_NACC) return;
    float v = ld_f(x, i, f32) + acc[i];
    v = fmaxf(v, 0.0f);
    if (f32) ((float*)out)[i] = v;
    else     ((__hip_bfloat16*)out)[i] = __float2bfloat16(v);
}

// ===========================================================================
extern "C" void kernel_launch(void* const* d_in, const int* in_sizes, int n_in,
                              void* d_out, int out_size, void* d_ws, size_t ws_size,
                              hipStream_t stream)
{
    const void* x  = d_in[0];
    const void* ei = d_in[1];
    const void* W1 = d_in[2];
    const void* b1 = d_in[3];
    const void* W2 = d_in[4];
    const void* b2 = d_in[5];

    int blk = 256;
    if (ws_size >= CSR_NEEDED_BYTES) {
        int* wsI = (int*)d_ws;
        csr_init_kernel<<<(4 * N_NODES + blk - 1) / blk, blk, 0, stream>>>(wsI, x, ei);
        csr_count_kernel<<<(N_EDGES + blk - 1) / blk, blk, 0, stream>>>(ei, wsI);
        csr_scan1_kernel<<<SCAN_G, SCAN_B, 0, stream>>>(wsI);
        csr_scan3_kernel<<<SCAN_G, SCAN_B, 0, stream>>>(wsI);
        csr_edge_kernel<<<(N_EDGES + blk - 1) / blk, blk, 0, stream>>>(x, ei, W1, b1, W2, b2, wsI);
        csr_gather_kernel<<<(N_NODES + 63) / 64, blk, 0, stream>>>(x, wsI, d_out);
    } else {
        float* ws = (float*)d_ws;
        fb_init_kernel<<<(FB_FLAGS + blk - 1) / blk, blk, 0, stream>>>(ws, x, ei);
        fb_deg_kernel<<<(N_EDGES + blk - 1) / blk, blk, 0, stream>>>(ei, ws);
        fb_edge_kernel<<<(N_EDGES + blk - 1) / blk, blk, 0, stream>>>(x, ei, W1, b1, W2, b2, ws);
        fb_finalize_kernel<<<(FB_NACC + blk - 1) / blk, blk, 0, stream>>>(x, ws, d_out);
    }
}